// Round 1
// baseline (373.036 us; speedup 1.0000x reference)
//
#include <hip/hip_runtime.h>
#include <stdint.h>

// Problem constants (fixed by reference setup_inputs)
#define BATCH 128
#define W_LEN 8192
#define D_FEAT 64
#define WC 128            // w rows staged per chunk
#define LDS_STRIDE 68     // uints per feature row: 64 pairs + pad 4 (keeps 16B align, breaks pow2 banks)
#define WS_PER_SLICE 4160 // 4096 cov partial + 64 feature-sum partial (floats)

typedef __bf16 bf16x8 __attribute__((ext_vector_type(8)));
typedef float f32x4 __attribute__((ext_vector_type(4)));

union FragU { uint4 u; bf16x8 v; };

// round-to-nearest-even fp32 -> bf16, packed pair (lo = even w, hi = odd w)
__device__ __forceinline__ unsigned int f2bf_pair(float lo, float hi) {
  unsigned int a = __float_as_uint(lo);
  unsigned int b = __float_as_uint(hi);
  a = (a + 0x7fffu + ((a >> 16) & 1u)) >> 16;
  b = (b + 0x7fffu + ((b >> 16) & 1u)) >> 16;
  return (a & 0xffffu) | (b << 16);
}

// Kernel 1: per (batch b, w-slice s) compute partial Sum_w x[w,i]*x[w,j] (bf16 MFMA,
// fp32 accum) and partial Sum_w x[w,d] (fp32), write to ws.
__global__ void __launch_bounds__(256)
cov_partial_kernel(const float* __restrict__ x, float* __restrict__ ws, int S) {
  __shared__ __align__(16) unsigned int lds_u[D_FEAT * LDS_STRIDE]; // 17408 B; reused as fp32 cov[4096]
  __shared__ float ssum_scratch[256 * 4];
  const int tid  = threadIdx.x;
  const int lane = tid & 63;
  const int wid  = tid >> 6;     // wave id 0..3
  const int s = blockIdx.x;
  const int b = blockIdx.y;
  const int ws_per   = W_LEN / S;
  const int nchunks  = ws_per / WC;

  const int q    = tid & 15;     // d-quad owned during staging (d = 4q..4q+3)
  const int prow = tid >> 4;     // 0..15
  const int m    = lane & 15;    // MFMA fragment row/col within 16-tile
  const int hi   = lane >> 4;    // 0..3
  const int koff = wid * 16 + hi * 4;   // uint offset into a feature row (wave's K=32 slice)

  f32x4 acc[4][4];
  #pragma unroll
  for (int i = 0; i < 4; i++)
    #pragma unroll
    for (int j = 0; j < 4; j++)
      #pragma unroll
      for (int r = 0; r < 4; r++) acc[i][j][r] = 0.0f;

  float ssum[4] = {0.f, 0.f, 0.f, 0.f};

  const size_t base_row = (size_t)b * W_LEN + (size_t)s * ws_per;

  for (int c = 0; c < nchunks; c++) {
    __syncthreads();   // previous chunk's MFMA reads done; staging buffer free
    // ---- stage chunk c: rows [c*WC, c*WC+WC), transposed+packed into LDS ----
    #pragma unroll
    for (int it = 0; it < 4; it++) {
      const int p = it * 16 + prow;  // w-pair index 0..63
      const float* src = x + (base_row + (size_t)c * WC + 2 * p) * D_FEAT + q * 4;
      float4 fa = *(const float4*)(src);
      float4 fb = *(const float4*)(src + D_FEAT);
      ssum[0] += fa.x + fb.x;
      ssum[1] += fa.y + fb.y;
      ssum[2] += fa.z + fb.z;
      ssum[3] += fa.w + fb.w;
      lds_u[(q * 4 + 0) * LDS_STRIDE + p] = f2bf_pair(fa.x, fb.x);
      lds_u[(q * 4 + 1) * LDS_STRIDE + p] = f2bf_pair(fa.y, fb.y);
      lds_u[(q * 4 + 2) * LDS_STRIDE + p] = f2bf_pair(fa.z, fb.z);
      lds_u[(q * 4 + 3) * LDS_STRIDE + p] = f2bf_pair(fa.w, fb.w);
    }
    __syncthreads();
    // ---- MFMA: wave `wid` contracts its K=32 slice of this chunk ----
    FragU f[4];
    #pragma unroll
    for (int g = 0; g < 4; g++)
      f[g].u = *(const uint4*)&lds_u[(g * 16 + m) * LDS_STRIDE + koff];
    #pragma unroll
    for (int i = 0; i < 4; i++)
      #pragma unroll
      for (int j = 0; j < 4; j++)
        acc[i][j] = __builtin_amdgcn_mfma_f32_16x16x32_bf16(f[i].v, f[j].v, acc[i][j], 0, 0, 0);
  }

  __syncthreads();
  // ---- reduce the 4 per-wave 64x64 accumulators into LDS (reuse staging) ----
  float* cov_lds = (float*)lds_u;  // 4096 floats
  for (int wv = 0; wv < 4; wv++) {
    if (wid == wv) {
      #pragma unroll
      for (int i = 0; i < 4; i++)
        #pragma unroll
        for (int j = 0; j < 4; j++)
          #pragma unroll
          for (int r = 0; r < 4; r++) {
            // C/D layout (m89-verified): col = lane&15, row = (lane>>4)*4 + reg
            const int row = i * 16 + hi * 4 + r;
            const int col = j * 16 + m;
            const int idx = row * D_FEAT + col;
            if (wv == 0) cov_lds[idx] = acc[i][j][r];
            else         cov_lds[idx] += acc[i][j][r];
          }
    }
    __syncthreads();
  }

  // ---- feature-sum block reduction ----
  #pragma unroll
  for (int j = 0; j < 4; j++) ssum_scratch[tid * 4 + j] = ssum[j];
  __syncthreads();

  float* out_base = ws + (size_t)(b * S + s) * WS_PER_SLICE;
  if (tid < D_FEAT) {
    const int qq = tid >> 2, jj = tid & 3;
    float t = 0.f;
    #pragma unroll
    for (int g = 0; g < 16; g++) t += ssum_scratch[(g * 16 + qq) * 4 + jj];
    out_base[4096 + tid] = t;
  }
  #pragma unroll
  for (int it = 0; it < 4; it++) {
    const int idx = (it * 256 + tid) * 4;
    *(float4*)&out_base[idx] = *(const float4*)&cov_lds[idx];
  }
}

// Kernel 2: reduce S partials per batch, mean-correct, std, threshold-count, -1.
__global__ void __launch_bounds__(256)
corr_count_kernel(const float* __restrict__ ws, float* __restrict__ out, int S) {
  __shared__ __align__(16) float cov[4096];
  __shared__ float sums[D_FEAT];
  __shared__ float rstd[D_FEAT];
  __shared__ float cnts[256];
  const int tid = threadIdx.x;
  const int b = blockIdx.x;
  const float* base = ws + (size_t)b * S * WS_PER_SLICE;

  #pragma unroll
  for (int it = 0; it < 4; it++) {
    const int idx = (it * 256 + tid) * 4;
    float ax = 0.f, ay = 0.f, az = 0.f, aw = 0.f;
    for (int s = 0; s < S; s++) {
      float4 v = *(const float4*)&base[(size_t)s * WS_PER_SLICE + idx];
      ax += v.x; ay += v.y; az += v.z; aw += v.w;
    }
    float4 a; a.x = ax; a.y = ay; a.z = az; a.w = aw;
    *(float4*)&cov[idx] = a;
  }
  if (tid < D_FEAT) {
    float t = 0.f;
    for (int s = 0; s < S; s++) t += base[(size_t)s * WS_PER_SLICE + 4096 + tid];
    sums[tid] = t;
  }
  __syncthreads();
  if (tid < D_FEAT) {
    const float sd = sums[tid];
    float c = (cov[tid * D_FEAT + tid] - sd * sd * (1.0f / W_LEN)) * (1.0f / (W_LEN - 1));
    c = c > 0.f ? c : 0.f;
    rstd[tid] = 1.0f / (sqrtf(c) + 1e-8f);
  }
  __syncthreads();
  {
    const int r = tid >> 2, part = tid & 3;
    const float sr = sums[r];
    const float rs_r = rstd[r];
    float cnt = 0.f;
    #pragma unroll
    for (int k = 0; k < 16; k++) {
      const int cc = part * 16 + k;
      const float cv = (cov[r * D_FEAT + cc] - sr * sums[cc] * (1.0f / W_LEN)) * (1.0f / (W_LEN - 1));
      const float corr = cv * rs_r * rstd[cc];
      cnt += (fabsf(corr) > 0.3f) ? 1.0f : 0.0f;
    }
    cnts[tid] = cnt;
  }
  __syncthreads();
  if (tid < D_FEAT) {
    const float t = cnts[tid * 4] + cnts[tid * 4 + 1] + cnts[tid * 4 + 2] + cnts[tid * 4 + 3];
    out[(size_t)b * D_FEAT + tid] = t - 1.0f;
  }
}

extern "C" void kernel_launch(void* const* d_in, const int* in_sizes, int n_in,
                              void* d_out, int out_size, void* d_ws, size_t ws_size,
                              hipStream_t stream) {
  const float* x = (const float*)d_in[0];
  float* out = (float*)d_out;
  float* ws  = (float*)d_ws;

  int S = 8;  // W-splits: 1024 blocks for kernel 1
  while (S > 1 && (size_t)BATCH * S * WS_PER_SLICE * sizeof(float) > ws_size) S >>= 1;

  dim3 g1(S, BATCH);
  cov_partial_kernel<<<g1, 256, 0, stream>>>(x, ws, S);
  corr_count_kernel<<<BATCH, 256, 0, stream>>>(ws, out, S);
}

// Round 2
// 366.595 us; speedup vs baseline: 1.0176x; 1.0176x over previous
//
#include <hip/hip_runtime.h>
#include <stdint.h>

// Problem constants (fixed by reference setup_inputs)
#define BATCH 128
#define W_LEN 8192
#define D_FEAT 64
#define WC 128            // w rows staged per chunk
#define LDS_STRIDE 68     // uints per feature row: 64 pairs + pad 4 (16B-aligned rows)
#define LDSU (D_FEAT * LDS_STRIDE)   // 4352 uints per buffer
#define WS_PER_SLICE 4160 // 4096 cov partial + 64 feature-sum partial (floats)

typedef __bf16 bf16x8 __attribute__((ext_vector_type(8)));
typedef float f32x4 __attribute__((ext_vector_type(4)));

union FragU { uint4 u; bf16x8 v; };

// pack (lo = bf16(a), hi = bf16(b)) via one v_perm_b32 (truncation: 27-sigma margin)
__device__ __forceinline__ unsigned int pack_bf16_pair(float a, float b) {
  return __builtin_amdgcn_perm(__float_as_uint(b), __float_as_uint(a), 0x07060302u);
}

// Kernel 1: per (batch b, w-slice s) compute partial Sum_w x[w,i]*x[w,j] (bf16 MFMA,
// fp32 accum) and partial Sum_w x[w,d] (fp32), write to ws.
// Staging: thread (q = tid&15, T = tid>>4) owns w-rows 8T..8T+7, feats 4q..4q+3 of the
// chunk; packs to 4 x uint4 and writes with ds_write_b128 (conflict-free banking).
// Compute: wave wid owns output rows 16*wid..16*wid+15, all 64 cols; full K per chunk.
__global__ void __launch_bounds__(256, 4)
cov_partial_kernel(const float* __restrict__ x, float* __restrict__ ws, int S) {
  __shared__ __align__(16) unsigned int lds_u[2][LDSU]; // 34816 B, double-buffered
  __shared__ float ssum_scratch[256 * 4];               // 4096 B
  const int tid  = threadIdx.x;
  const int lane = tid & 63;
  const int wid  = tid >> 6;     // wave id 0..3
  const int s = blockIdx.x;
  const int b = blockIdx.y;
  const int ws_per  = W_LEN / S;
  const int nchunks = ws_per / WC;

  const int q = tid & 15;        // feat quad (cols 4q..4q+3)
  const int T = tid >> 4;        // w-octet within chunk (rows 8T..8T+7)
  const int m  = lane & 15;      // MFMA fragment row/col within 16-tile
  const int hi = lane >> 4;      // 0..3

  f32x4 acc[4];                  // 4 col-tiles of this wave's 16-row slab
  #pragma unroll
  for (int t = 0; t < 4; t++)
    #pragma unroll
    for (int r = 0; r < 4; r++) acc[t][r] = 0.0f;

  float ssum[4] = {0.f, 0.f, 0.f, 0.f};

  const size_t base = ((size_t)b * W_LEN + (size_t)s * ws_per) * D_FEAT;
  const float* src0 = x + base + (size_t)(8 * T) * D_FEAT + 4 * q;

  // prologue: prefetch chunk 0 into registers
  float4 ld[8];
  #pragma unroll
  for (int r = 0; r < 8; r++) ld[r] = *(const float4*)(src0 + r * D_FEAT);

  for (int c = 0; c < nchunks; c++) {
    unsigned int* buf = lds_u[c & 1];
    // ---- pack + feature-sum + b128 LDS write ----
    #pragma unroll
    for (int j = 0; j < 4; j++) {
      const float* f0 = (const float*)&ld[0];
      uint4 pk;
      pk.x = pack_bf16_pair(f0[0 * 4 + j], f0[1 * 4 + j]);
      pk.y = pack_bf16_pair(f0[2 * 4 + j], f0[3 * 4 + j]);
      pk.z = pack_bf16_pair(f0[4 * 4 + j], f0[5 * 4 + j]);
      pk.w = pack_bf16_pair(f0[6 * 4 + j], f0[7 * 4 + j]);
      ssum[j] += ((f0[0 * 4 + j] + f0[1 * 4 + j]) + (f0[2 * 4 + j] + f0[3 * 4 + j]))
               + ((f0[4 * 4 + j] + f0[5 * 4 + j]) + (f0[6 * 4 + j] + f0[7 * 4 + j]));
      *(uint4*)&buf[(4 * q + j) * LDS_STRIDE + 4 * T] = pk;
    }
    // ---- prefetch next chunk (overlaps barrier + MFMA below) ----
    if (c + 1 < nchunks) {
      const float* srcn = src0 + (size_t)(c + 1) * WC * D_FEAT;
      #pragma unroll
      for (int r = 0; r < 8; r++) ld[r] = *(const float4*)(srcn + r * D_FEAT);
    }
    __syncthreads();
    // ---- MFMA: wave's 16-row slab x all 64 cols, full K=128 of this chunk ----
    #pragma unroll
    for (int st = 0; st < 4; st++) {
      const int ko = st * 16 + hi * 4;
      FragU fA;
      fA.u = *(const uint4*)&buf[(16 * wid + m) * LDS_STRIDE + ko];
      #pragma unroll
      for (int t = 0; t < 4; t++) {
        FragU fB;
        fB.u = *(const uint4*)&buf[(16 * t + m) * LDS_STRIDE + ko];
        acc[t] = __builtin_amdgcn_mfma_f32_16x16x32_bf16(fA.v, fB.v, acc[t], 0, 0, 0);
      }
    }
  }

  // ---- epilogue: direct store (wave owns its rows exclusively) ----
  float* out_base = ws + (size_t)(b * S + s) * WS_PER_SLICE;
  #pragma unroll
  for (int t = 0; t < 4; t++)
    #pragma unroll
    for (int r = 0; r < 4; r++) {
      // C/D layout (m89-verified): col = lane&15, row = (lane>>4)*4 + reg
      const int row = 16 * wid + hi * 4 + r;
      const int col = 16 * t + m;
      out_base[row * D_FEAT + col] = acc[t][r];
    }

  // ---- feature-sum block reduction ----
  #pragma unroll
  for (int j = 0; j < 4; j++) ssum_scratch[tid * 4 + j] = ssum[j];
  __syncthreads();
  if (tid < D_FEAT) {
    const int qq = tid >> 2, jj = tid & 3;
    float t = 0.f;
    #pragma unroll
    for (int g = 0; g < 16; g++) t += ssum_scratch[(g * 16 + qq) * 4 + jj];
    out_base[4096 + tid] = t;
  }
}

// Kernel 2: reduce S partials per batch, mean-correct, std, threshold-count, -1.
__global__ void __launch_bounds__(256)
corr_count_kernel(const float* __restrict__ ws, float* __restrict__ out, int S) {
  __shared__ __align__(16) float cov[4096];
  __shared__ float sums[D_FEAT];
  __shared__ float rstd[D_FEAT];
  __shared__ float cnts[256];
  const int tid = threadIdx.x;
  const int b = blockIdx.x;
  const float* base = ws + (size_t)b * S * WS_PER_SLICE;

  #pragma unroll
  for (int it = 0; it < 4; it++) {
    const int idx = (it * 256 + tid) * 4;
    float ax = 0.f, ay = 0.f, az = 0.f, aw = 0.f;
    for (int s = 0; s < S; s++) {
      float4 v = *(const float4*)&base[(size_t)s * WS_PER_SLICE + idx];
      ax += v.x; ay += v.y; az += v.z; aw += v.w;
    }
    float4 a; a.x = ax; a.y = ay; a.z = az; a.w = aw;
    *(float4*)&cov[idx] = a;
  }
  if (tid < D_FEAT) {
    float t = 0.f;
    for (int s = 0; s < S; s++) t += base[(size_t)s * WS_PER_SLICE + 4096 + tid];
    sums[tid] = t;
  }
  __syncthreads();
  if (tid < D_FEAT) {
    const float sd = sums[tid];
    float c = (cov[tid * D_FEAT + tid] - sd * sd * (1.0f / W_LEN)) * (1.0f / (W_LEN - 1));
    c = c > 0.f ? c : 0.f;
    rstd[tid] = 1.0f / (sqrtf(c) + 1e-8f);
  }
  __syncthreads();
  {
    const int r = tid >> 2, part = tid & 3;
    const float sr = sums[r];
    const float rs_r = rstd[r];
    float cnt = 0.f;
    #pragma unroll
    for (int k = 0; k < 16; k++) {
      const int cc = part * 16 + k;
      const float cv = (cov[r * D_FEAT + cc] - sr * sums[cc] * (1.0f / W_LEN)) * (1.0f / (W_LEN - 1));
      const float corr = cv * rs_r * rstd[cc];
      cnt += (fabsf(corr) > 0.3f) ? 1.0f : 0.0f;
    }
    cnts[tid] = cnt;
  }
  __syncthreads();
  if (tid < D_FEAT) {
    const float t = cnts[tid * 4] + cnts[tid * 4 + 1] + cnts[tid * 4 + 2] + cnts[tid * 4 + 3];
    out[(size_t)b * D_FEAT + tid] = t - 1.0f;
  }
}

extern "C" void kernel_launch(void* const* d_in, const int* in_sizes, int n_in,
                              void* d_out, int out_size, void* d_ws, size_t ws_size,
                              hipStream_t stream) {
  const float* x = (const float*)d_in[0];
  float* out = (float*)d_out;
  float* ws  = (float*)d_ws;

  int S = 8;  // W-splits: 1024 blocks for kernel 1
  while (S > 1 && (size_t)BATCH * S * WS_PER_SLICE * sizeof(float) > ws_size) S >>= 1;

  dim3 g1(S, BATCH);
  cov_partial_kernel<<<g1, 256, 0, stream>>>(x, ws, S);
  corr_count_kernel<<<BATCH, 256, 0, stream>>>(ws, out, S);
}